// Round 15
// baseline (304.433 us; speedup 1.0000x reference)
//
#include <hip/hip_runtime.h>

// ---------------------------------------------------------------------------
// ConditionalCrossAttentionBlock: LN -> K/V proj -> RMS(Q proj) -> RoPE ->
// 16-head cross attention (LQ=4096, LKV=1024, Dh=128) -> O proj.
// R15: attention split into 256-thread blocks (4 waves x 32 q, KVBLK=64,
// LDS 64KB) -> 2 independent blocks/CU; barrier drains of one block overlap
// MFMA of the other (m114). Per-wave math identical to proven R8/R10.
// Rest unchanged from R14 (5 launches).
// ---------------------------------------------------------------------------

typedef __attribute__((ext_vector_type(8))) short    short8;
typedef __attribute__((ext_vector_type(8))) unsigned short ushort8;
typedef __attribute__((ext_vector_type(4))) unsigned short ushort4v;
typedef __attribute__((ext_vector_type(4))) float    f32x4;
typedef __attribute__((ext_vector_type(16))) float   f32x16;
typedef __attribute__((ext_vector_type(4))) unsigned int uint4v;

#define DEV __device__ __forceinline__

DEV unsigned short f2bf(float f) {
  unsigned int u = __builtin_bit_cast(unsigned int, f);
  u += 0x7FFFu + ((u >> 16) & 1u);        // RNE, inputs are finite
  return (unsigned short)(u >> 16);
}
DEV float bf2f(unsigned short h) {
  return __builtin_bit_cast(float, ((unsigned int)h) << 16);
}
DEV unsigned int cvtpk_bf16(float lo, float hi) {
  unsigned int r;
  asm("v_cvt_pk_bf16_f32 %0, %1, %2" : "=v"(r) : "v"(lo), "v"(hi));
  return r;
}
DEV short8 mk8(unsigned a, unsigned b, unsigned c, unsigned d) {
  uint4v t; t.x = a; t.y = b; t.z = c; t.w = d;
  return __builtin_bit_cast(short8, t);
}

DEV void gload_lds16(const void* g, void* l) {
  __builtin_amdgcn_global_load_lds(
      (const __attribute__((address_space(1))) void*)g,
      (__attribute__((address_space(3))) void*)l, 16, 0, 0);
}

// ---------------------------------------------------------------------------
// prep: blocks [0,2048) = LayerNorm rows; [2048,3584) = grid-stride f32->bf16
// over {x, Wq, Wk, Wv, Wo}.
// ---------------------------------------------------------------------------
__global__ __launch_bounds__(256) void prep_kernel(const float* __restrict__ y,
                                                   const float* __restrict__ lnw,
                                                   const float* __restrict__ lnb,
                                                   unsigned short* __restrict__ yn,
                                                   const float* __restrict__ x,
                                                   const float* __restrict__ Wq,
                                                   const float* __restrict__ Wk,
                                                   const float* __restrict__ Wv,
                                                   const float* __restrict__ Wo,
                                                   unsigned short* __restrict__ xb,
                                                   unsigned short* __restrict__ Wqb,
                                                   unsigned short* __restrict__ Wkb,
                                                   unsigned short* __restrict__ Wvb,
                                                   unsigned short* __restrict__ Wob) {
  const int t = threadIdx.x;
  if (blockIdx.x < 2048) {
    const int row = blockIdx.x;
    const float* yr = y + (size_t)row * 1024;
    float4 v = *(const float4*)(yr + t * 4);
    float s1 = v.x + v.y + v.z + v.w;
    float s2 = v.x * v.x + v.y * v.y + v.z * v.z + v.w * v.w;
#pragma unroll
    for (int m = 1; m < 64; m <<= 1) {
      s1 += __shfl_xor(s1, m);
      s2 += __shfl_xor(s2, m);
    }
    __shared__ float red[8];
    const int wave = t >> 6, lane = t & 63;
    if (lane == 0) { red[wave] = s1; red[4 + wave] = s2; }
    __syncthreads();
    s1 = red[0] + red[1] + red[2] + red[3];
    s2 = red[4] + red[5] + red[6] + red[7];
    const float mu = s1 * (1.0f / 1024.0f);
    const float var = s2 * (1.0f / 1024.0f) - mu * mu;
    const float rs = rsqrtf(var + 1e-6f);
    ushort4v o;
    o.x = f2bf((v.x - mu) * rs * lnw[t * 4 + 0] + lnb[t * 4 + 0]);
    o.y = f2bf((v.y - mu) * rs * lnw[t * 4 + 1] + lnb[t * 4 + 1]);
    o.z = f2bf((v.z - mu) * rs * lnw[t * 4 + 2] + lnb[t * 4 + 2]);
    o.w = f2bf((v.w - mu) * rs * lnw[t * 4 + 3] + lnb[t * 4 + 3]);
    *(ushort4v*)(yn + (size_t)row * 1024 + t * 4) = o;
    return;
  }
  const int nx = 4194304, nwq = 1048576, nwk = 524288, nwv = 524288;
  const int total = 7340032;
  int i = (blockIdx.x - 2048) * 256 + t;
  const int stride = 1536 * 256;
  for (; i < total; i += stride) {
    int j = i;
    const float* s; unsigned short* d;
    if (j < nx) { s = x; d = xb; }
    else if ((j -= nx) < nwq) { s = Wq; d = Wqb; }
    else if ((j -= nwq) < nwk) { s = Wk; d = Wkb; }
    else if ((j -= nwk) < nwv) { s = Wv; d = Wvb; }
    else { j -= nwv; s = Wo; d = Wob; }
    float4 v = *(const float4*)(s + (size_t)j * 4);
    ushort4v o;
    o.x = f2bf(v.x); o.y = f2bf(v.y); o.z = f2bf(v.z); o.w = f2bf(v.w);
    *(ushort4v*)(d + (size_t)j * 4) = o;
  }
}

// ---------------------------------------------------------------------------
// 256x256 8-phase pipelined GEMM body (T2+T3+T4+T5).
// C = A[M,K]@W[N,K]^T (+bias). ldRow = row stride in elements (>= K).
// EPI==0: bf16 out + bias; EPI==1: f32 out + bias; EPI==2: bf16 out, no bias.
// ---------------------------------------------------------------------------
template <int EPI>
DEV void gemm256_body(const unsigned short* __restrict__ A,
                      const unsigned short* __restrict__ W,
                      const float* __restrict__ bias0,
                      const float* __restrict__ bias1,
                      int nsplit, void* __restrict__ Cout,
                      int M, int N, int K, int ldRow,
                      int bidLocal, int nwg, char* ldsb, int tid) {
  const int wave = tid >> 6, lane = tid & 63;
  const int lg = lane >> 4, l15 = lane & 15;
  const int wm = wave >> 2, wn = wave & 3;

  const int wgid = (bidLocal & 7) * (nwg >> 3) + (bidLocal >> 3);
  const int nbn = N >> 8;
  const int m0 = (wgid / nbn) * 256;
  const int n0 = (wgid % nbn) * 256;

  const char* Ab = (const char*)A;
  const char* Wb = (const char*)W;
  const size_t ld = (size_t)ldRow * 2;
  const int NT = K >> 6;
  const int NI = NT >> 1;

  const int prow = tid >> 3;
  const int psw  = ((tid * 16) & 127) ^ ((prow & 7) << 4);
  const int pdst = tid * 16;
  const char* pAg = Ab + (size_t)(m0 + prow) * ld + psw;
  const char* pBg = Wb + (size_t)(n0 + prow) * ld + psw;

  f32x4 acc[8][4] = {};
  short8 af[4][2];
  short8 bf[4][2];

#define LDSB(BUF, SEG) (ldsb + ((BUF) * 4 + (SEG)) * 16384)

#define STG(BUF, HALF, ISB, TAU) do {                                         \
    const char* _g = ((ISB) ? pBg : pAg) + (size_t)(HALF) * 128 * ld +        \
                     (size_t)(TAU) * 128;                                     \
    char* _l = LDSB(BUF, (ISB) * 2 + (HALF));                                 \
    gload_lds16(_g, _l + pdst);                                               \
    gload_lds16(_g + 64 * ld, _l + pdst + 8192);                              \
  } while (0)

#define LDA(BUF, H) do {                                                      \
    const char* _b = LDSB(BUF, wm);                                           \
    _Pragma("unroll") for (int mfl = 0; mfl < 4; ++mfl) {                     \
      const int _r = (H) * 64 + mfl * 16 + l15;                               \
      _Pragma("unroll") for (int ks = 0; ks < 2; ++ks)                        \
        af[mfl][ks] = *(const short8*)(_b + _r * 128 +                        \
                        ((ks * 64 + lg * 16) ^ ((_r & 7) << 4)));             \
    }                                                                         \
  } while (0)

#define LDB(BUF, G) do {                                                      \
    const char* _b = LDSB(BUF, 2 + (wn >> 1));                                \
    _Pragma("unroll") for (int nfl = 0; nfl < 2; ++nfl) {                     \
      const int _r = (wn & 1) * 64 + (G) * 32 + nfl * 16 + l15;               \
      _Pragma("unroll") for (int ks = 0; ks < 2; ++ks)                        \
        bf[(G) * 2 + nfl][ks] = *(const short8*)(_b + _r * 128 +              \
                        ((ks * 64 + lg * 16) ^ ((_r & 7) << 4)));             \
    }                                                                         \
  } while (0)

#define MFMA_Q(H, G) do {                                                     \
    __builtin_amdgcn_s_setprio(1);                                            \
    _Pragma("unroll") for (int ks = 0; ks < 2; ++ks)                          \
    _Pragma("unroll") for (int mfl = 0; mfl < 4; ++mfl)                       \
    _Pragma("unroll") for (int nfl = 0; nfl < 2; ++nfl)                       \
      acc[(H) * 4 + mfl][(G) * 2 + nfl] =                                     \
        __builtin_amdgcn_mfma_f32_16x16x32_bf16(af[mfl][ks],                  \
            bf[(G) * 2 + nfl][ks], acc[(H) * 4 + mfl][(G) * 2 + nfl], 0,0,0); \
    __builtin_amdgcn_s_setprio(0);                                            \
  } while (0)

#define BAR() __builtin_amdgcn_s_barrier()
#define LGKM0() do { asm volatile("s_waitcnt lgkmcnt(0)" ::: "memory");       \
    __builtin_amdgcn_sched_barrier(0); } while (0)
#define VM4() asm volatile("s_waitcnt vmcnt(4)" ::: "memory")
#define VM0() asm volatile("s_waitcnt vmcnt(0)" ::: "memory")

  STG(0, 0, 0, 0); STG(0, 1, 0, 0); STG(0, 0, 1, 0); STG(0, 1, 1, 0);
  STG(1, 0, 1, 1); STG(1, 1, 1, 1);
  VM4(); BAR();

  for (int t = 0; t < NI - 1; ++t) {
    const int t2 = 2 * t;
    LDA(0, 0); LDB(0, 0); STG(1, 0, 0, t2 + 1);
    BAR(); LGKM0(); MFMA_Q(0, 0); BAR();
    LDB(0, 1); STG(1, 1, 0, t2 + 1);
    BAR(); LGKM0(); MFMA_Q(0, 1); BAR();
    LDA(0, 1); STG(0, 0, 1, t2 + 2);
    BAR(); LGKM0(); MFMA_Q(1, 1); BAR();
    STG(0, 1, 1, t2 + 2);
    BAR(); MFMA_Q(1, 0); VM4(); BAR();
    LDA(1, 0); LDB(1, 0); STG(0, 0, 0, t2 + 2);
    BAR(); LGKM0(); MFMA_Q(0, 0); BAR();
    LDB(1, 1); STG(0, 1, 0, t2 + 2);
    BAR(); LGKM0(); MFMA_Q(0, 1); BAR();
    LDA(1, 1); STG(1, 0, 1, t2 + 3);
    BAR(); LGKM0(); MFMA_Q(1, 1); BAR();
    STG(1, 1, 1, t2 + 3);
    BAR(); MFMA_Q(1, 0); VM4(); BAR();
  }

  LDA(0, 0); LDB(0, 0); STG(1, 0, 0, NT - 1);
  BAR(); LGKM0(); MFMA_Q(0, 0); BAR();
  LDB(0, 1); STG(1, 1, 0, NT - 1);
  BAR(); LGKM0(); MFMA_Q(0, 1); BAR();
  LDA(0, 1);
  BAR(); LGKM0(); MFMA_Q(1, 1); BAR();
  BAR(); MFMA_Q(1, 0); VM0(); BAR();
  LDA(1, 0); LDB(1, 0); LGKM0(); MFMA_Q(0, 0);
  LDB(1, 1); LGKM0(); MFMA_Q(0, 1);
  LDA(1, 1); LGKM0(); MFMA_Q(1, 1);
  MFMA_Q(1, 0);

#undef STG
#undef LDA
#undef LDB
#undef MFMA_Q
#undef BAR
#undef LGKM0
#undef VM4
#undef VM0
#undef LDSB

#pragma unroll
  for (int nf = 0; nf < 4; ++nf) {
    const int n = n0 + wn * 64 + nf * 16 + l15;
    float bv = 0.f;
    if constexpr (EPI != 2) bv = (n < nsplit) ? bias0[n] : bias1[n - nsplit];
#pragma unroll
    for (int mf = 0; mf < 8; ++mf) {
      const int mB = m0 + wm * 128 + mf * 16 + lg * 4;
#pragma unroll
      for (int r = 0; r < 4; ++r) {
        const float v = acc[mf][nf][r] + bv;
        if constexpr (EPI == 1)
          ((float*)Cout)[(size_t)(mB + r) * N + n] = v;
        else
          ((unsigned short*)Cout)[(size_t)(mB + r) * N + n] = f2bf(v);
      }
    }
  }
}

// Every block: Q tile (32 units) then one KV K-half tile (8 units). Grid 256.
__global__ __launch_bounds__(512, 2) void gemm_dual(const unsigned short* __restrict__ xb,
                                                    const unsigned short* __restrict__ Wqb,
                                                    const float* __restrict__ bq,
                                                    unsigned short* __restrict__ qpre,
                                                    const unsigned short* __restrict__ ynb,
                                                    const unsigned short* __restrict__ Wkb,
                                                    unsigned short* __restrict__ kvpA,
                                                    unsigned short* __restrict__ kvpB) {
  __shared__ __align__(16) char lds[2][4][16384];
  gemm256_body<0>(xb, Wqb, bq, bq, 2048, qpre, 8192, 2048, 2048, 2048,
                  blockIdx.x, 256, &lds[0][0][0], threadIdx.x);
  __syncthreads();   // all waves done with LDS before restaging
  const int kvt = blockIdx.x & 127, khalf = blockIdx.x >> 7;
  gemm256_body<2>(ynb + khalf * 512, Wkb + khalf * 512, nullptr, nullptr, 0,
                  khalf ? kvpB : kvpA, 2048, 4096, 512, 1024,
                  kvt, 128, &lds[0][0][0], threadIdx.x);
}

// O projection (f32 out).
__global__ __launch_bounds__(512, 2) void gemm_f32(const unsigned short* __restrict__ A,
                                                   const unsigned short* __restrict__ W,
                                                   const float* __restrict__ bias,
                                                   float* __restrict__ C,
                                                   int M, int N, int K) {
  __shared__ __align__(16) char lds[2][4][16384];
  gemm256_body<1>(A, W, bias, bias, N, C, M, N, K, K,
                  blockIdx.x, 256, &lds[0][0][0], threadIdx.x);
}

// ---------------------------------------------------------------------------
// post: blocks [0,8192) rmsrope_q; [8192,10240) rmsrope_k (sum partials +
// bias); [10240,10752) vtrans (sum partials + bias).
// ---------------------------------------------------------------------------
DEV void rmsrope2_body(const unsigned short* __restrict__ in,
                       const unsigned short* __restrict__ in2,
                       const float* __restrict__ bias,
                       const float* __restrict__ w,
                       const float* __restrict__ cs,
                       const float* __restrict__ sn,
                       unsigned short* __restrict__ out,
                       int L, int ldin, float scale, int row,
                       float* srow, float* red) {
  const int t = threadIdx.x;
  ushort8 v = *(const ushort8*)(in + (size_t)row * ldin + t * 8);
  float vals[8];
  if (in2) {
    ushort8 v2 = *(const ushort8*)(in2 + (size_t)row * ldin + t * 8);
#pragma unroll
    for (int j = 0; j < 8; ++j) vals[j] = bf2f(v[j]) + bf2f(v2[j]) + bias[t * 8 + j];
  } else {
#pragma unroll
    for (int j = 0; j < 8; ++j) vals[j] = bf2f(v[j]);
  }
  float ss = 0.f;
#pragma unroll
  for (int j = 0; j < 8; ++j) { ss += vals[j] * vals[j]; srow[t * 8 + j] = vals[j]; }
#pragma unroll
  for (int m = 1; m < 64; m <<= 1) ss += __shfl_xor(ss, m);
  const int wave = t >> 6, lane = t & 63;
  if (lane == 0) red[wave] = ss;
  __syncthreads();
  const float tot = red[0] + red[1] + red[2] + red[3];
  const float rms = rsqrtf(tot * (1.0f / 2048.0f) + 1e-6f);

  const int n0 = t * 8;
  const int d0 = n0 & 127;
  const int hh = n0 >> 7;
  const float sign = (d0 < 64) ? -1.0f : 1.0f;
  const float* cb = cs + (size_t)row * 128 + d0;
  const float* sb = sn + (size_t)row * 128 + d0;
  ushort8 ou;
#pragma unroll
  for (int j = 0; j < 8; ++j) {
    const float self = vals[j] * rms * w[n0 + j];
    const float part = srow[(n0 ^ 64) + j] * rms * w[(n0 ^ 64) + j];
    ou[j] = f2bf((self * cb[j] + sign * part * sb[j]) * scale);
  }
  const int b = row / L, l = row - (row / L) * L;
  *(ushort8*)(out + (((size_t)(b * 16 + hh)) * L + l) * 128 + d0) = ou;
}

DEV void vtrans2_body(const unsigned short* __restrict__ va,
                      const unsigned short* __restrict__ vb,
                      const float* __restrict__ bv,
                      unsigned short* __restrict__ vt, int ldv, int bid,
                      unsigned short (*lt)[130]) {
  const int kt = bid & 15, bh = bid >> 4;
  const int h = bh & 15, b = bh >> 4;
  const int t = threadIdx.x;
  const int i0 = t >> 4, c0 = (t & 15) * 8;
  const size_t sbase = ((size_t)(b * 1024 + kt * 64)) * ldv + h * 128;
#pragma unroll
  for (int ii = 0; ii < 4; ++ii) {
    const int i = i0 + ii * 16;
    ushort8 a = *(const ushort8*)(va + sbase + (size_t)i * ldv + c0);
    ushort8 bb = *(const ushort8*)(vb + sbase + (size_t)i * ldv + c0);
#pragma unroll
    for (int j = 0; j < 8; ++j)
      lt[i][c0 + j] = f2bf(bf2f(a[j]) + bf2f(bb[j]) + bv[h * 128 + c0 + j]);
  }
  __syncthreads();
  const int d0 = t >> 3, j0 = (t & 7) * 8;
  unsigned short* dst = vt + (size_t)bh * 128 * 1024 + kt * 64;
#pragma unroll
  for (int dd = 0; dd < 4; ++dd) {
    const int d = d0 + dd * 32;
    ushort8 o;
#pragma unroll
    for (int jj = 0; jj < 8; ++jj) o[jj] = lt[j0 + jj][d];
    *(ushort8*)(dst + (size_t)d * 1024 + j0) = o;
  }
}

__global__ __launch_bounds__(256) void post_kernel(const unsigned short* __restrict__ qpre,
                                                   const float* __restrict__ rmsq_w,
                                                   const float* __restrict__ x_cos,
                                                   const float* __restrict__ x_sin,
                                                   unsigned short* __restrict__ qr,
                                                   const unsigned short* __restrict__ kvpA,
                                                   const unsigned short* __restrict__ kvpB,
                                                   const float* __restrict__ bk,
                                                   const float* __restrict__ bv,
                                                   const float* __restrict__ rmsk_w,
                                                   const float* __restrict__ y_cos,
                                                   const float* __restrict__ y_sin,
                                                   unsigned short* __restrict__ kr,
                                                   unsigned short* __restrict__ vt,
                                                   float qscale) {
  __shared__ __align__(16) float srow[2048];
  __shared__ float red[4];
  __shared__ unsigned short lt[64][130];
  const int b = blockIdx.x;
  if (b < 8192) {
    rmsrope2_body(qpre, nullptr, nullptr, rmsq_w, x_cos, x_sin, qr,
                  4096, 2048, qscale, b, srow, red);
  } else if (b < 10240) {
    rmsrope2_body(kvpA, kvpB, bk, rmsk_w, y_cos, y_sin, kr,
                  1024, 4096, 1.0f, b - 8192, srow, red);
  } else {
    vtrans2_body(kvpA + 2048, kvpB + 2048, bv, vt, 4096, b - 10240, lt);
  }
}

// ---------------------------------------------------------------------------
// Flash cross-attention, R15: 256-thread blocks (4 waves x 32 q), KVBLK=64,
// LDS 64KB -> 2 independent blocks/CU. Per-wave math identical to R8/R10:
// swapped QK^T 32x32x16, K [kv][128d] swz (row&15)<<4, paired-d V, in-reg P.
// ---------------------------------------------------------------------------
__global__ __launch_bounds__(256, 2) void attn_kernel(const unsigned short* __restrict__ q,
                                                      const unsigned short* __restrict__ k,
                                                      const unsigned short* __restrict__ vt,
                                                      unsigned short* __restrict__ ao) {
  __shared__ __align__(16) char sK[2][64 * 256];    // [buf][kv 64][128 d]
  __shared__ __align__(16) char sV[2][64 * 256];    // [buf] paired-d

  // XCD-grouped swizzle: all 32 q-tiles of one bh land on one XCD.
  const int bid0 = blockIdx.x;                      // 1024 = 32 bh * 32 qtiles
  const int bid = (bid0 & 7) * 128 + (bid0 >> 3);
  const int qt = bid & 31, bh = bid >> 5;
  const int tid = threadIdx.x;
  const int wave = tid >> 6, lane = tid & 63;
  const int l31 = lane & 31, hi = lane >> 5;
  const bool hib = (hi != 0);

  const unsigned short* qbase = q + (((size_t)bh * 4096) + qt * 128 + wave * 32) * 128;
  const char* kbase = (const char*)(k + (size_t)bh * 1024 * 128);
  const char* vbase = (const char*)(vt + (size_t)bh * 128 * 1024);

  // Q as B-operand frags (32x32x16): col=q=l31, k(d) = step*16 + hi*8 + j
  short8 qb[8];
#pragma unroll
  for (int step = 0; step < 8; ++step)
    qb[step] = *(const short8*)(qbase + (size_t)l31 * 128 + step * 16 + hi * 8);

  f32x16 o[4] = {};        // o[dt]: O[q=crow(r,hi)][d=dt*32+l31]
  float lsum = 0.f;

// stage one 64-kv tile into buffer BUF (256 threads: 4 iters each for K, V)
#define STAGE_KV(BUF, KV0) do {                                              \
    _Pragma("unroll")                                                        \
    for (int i = 0; i < 4; ++i) {                                            \
      const int p = (i * 256 + tid) * 16;                                    \
      const int row = p >> 8;                                                \
      const int si = (p & 255) ^ ((row & 15) << 4);                          \
      gload_lds16(kbase + (size_t)((KV0) + row) * 256 + si, sK[BUF] + p);    \
    }                                                                        \
    _Pragma("unroll")                                                        \
    for (int i = 0; i < 4; ++i) {                                            \
      const int p = (i * 256 + tid) * 16;                                    \
      const int row = p >> 8;                                                \
      const int si = (p & 255) ^ ((row & 15) << 4);                          \
      const int d = 2 * row + (si >> 7);                                     \
      gload_lds16(vbase + (size_t)d * 2048 + (KV0) * 2 + (si & 127),         \
                  sV[BUF] + p);                                              \
    }                                                                        \
  } while (0)

#define QK(K, S0, S1) do {                                                   \
    const int ksw = (l31 & 15) << 4;                                         \
    _Pragma("unroll") for (int step = 0; step < 8; ++step) {                 \
      const int cb2 = step * 32 + hi * 16;                                   \
      short8 kf0 = *(const short8*)((K) + l31 * 256 + (cb2 ^ ksw));          \
      short8 kf1 = *(const short8*)((K) + (32 + l31) * 256 + (cb2 ^ ksw));   \
      S0 = __builtin_amdgcn_mfma_f32_32x32x16_bf16(kf0, qb[step], S0, 0,0,0);\
      S1 = __builtin_amdgcn_mfma_f32_32x32x16_bf16(kf1, qb[step], S1, 0,0,0);\
    }                                                                        \
  } while (0)

#define SOFTMAX_PV(V, SS, F) do {                                            \
    float p_[16];                                                            \
    _Pragma("unroll") for (int r = 0; r < 16; ++r) p_[r] = exp2f((SS)[r]);   \
    lsum += (((p_[0]+p_[1])+(p_[2]+p_[3])) + ((p_[4]+p_[5])+(p_[6]+p_[7])))  \
          + (((p_[8]+p_[9])+(p_[10]+p_[11])) + ((p_[12]+p_[13])+(p_[14]+p_[15])));\
    const unsigned w0 = cvtpk_bf16(p_[0], p_[1]),  w1 = cvtpk_bf16(p_[2], p_[3]), \
                   w2 = cvtpk_bf16(p_[4], p_[5]),  w3 = cvtpk_bf16(p_[6], p_[7]), \
                   w4 = cvtpk_bf16(p_[8], p_[9]),  w5 = cvtpk_bf16(p_[10], p_[11]),\
                   w6 = cvtpk_bf16(p_[12], p_[13]),w7 = cvtpk_bf16(p_[14], p_[15]);\
    const unsigned x0 = (unsigned)__shfl_xor((int)(hib ? w0 : w2), 32);      \
    const unsigned x1 = (unsigned)__shfl_xor((int)(hib ? w1 : w3), 32);      \
    const unsigned x2 = (unsigned)__shfl_xor((int)(hib ? w4 : w6), 32);      \
    const unsigned x3 = (unsigned)__shfl_xor((int)(hib ? w5 : w7), 32);      \
    const short8 fr0 = mk8(hib ? x0 : w0, hib ? x1 : w1,                     \
                           hib ? w2 : x0, hib ? w3 : x1);                    \
    const short8 fr1 = mk8(hib ? x2 : w4, hib ? x3 : w5,                     \
                           hib ? w6 : x2, hib ? w7 : x3);                    \
    _Pragma("unroll") for (int kstep = 0; kstep < 2; ++kstep) {              \
      const short8 pa = kstep ? fr1 : fr0;                                   \
      const int colb = (F) * 64 + kstep * 32 + hi * 16;                      \
      _Pragma("unroll") for (int dt = 0; dt < 4; ++dt) {                     \
        const int vrow = dt * 16 + (l31 >> 1);                               \
        const int inner = (l31 & 1) * 128 + colb;                            \
        short8 vf = *(const short8*)((V) + vrow * 256 +                      \
                                     (inner ^ ((vrow & 15) << 4)));          \
        o[dt] = __builtin_amdgcn_mfma_f32_32x32x16_bf16(pa, vf, o[dt], 0,0,0);\
      }                                                                      \
    }                                                                        \
  } while (0)

// one 64-kv tile: QK both 32-kv halves, then softmax+PV each
#define TILE(BUF) do {                                                       \
    f32x16 s0 = {}, s1 = {};                                                 \
    QK(sK[BUF], s0, s1);                                                     \
    SOFTMAX_PV(sV[BUF], s0, 0);                                              \
    SOFTMAX_PV(sV[BUF], s1, 1);                                              \
  } while (0)

  STAGE_KV(0, 0);
  __syncthreads();

#pragma unroll 1
  for (int kt2 = 0; kt2 < 8; ++kt2) {
    STAGE_KV(1, (2 * kt2 + 1) * 64);     // prefetch odd tile into buf1
    TILE(0);
    __syncthreads();
    if (kt2 < 7) STAGE_KV(0, (2 * kt2 + 2) * 64);  // prefetch even tile
    TILE(1);
    __syncthreads();
  }
#undef STAGE_KV
#undef QK
#undef SOFTMAX_PV
#undef TILE

  // ---- epilogue: denom(q=l31) = own half + partner half; redistribute ----
  lsum += __shfl_xor(lsum, 32);
  const float linv = 1.0f / lsum;
  const int b = bh >> 4, h = bh & 15;
#pragma unroll
  for (int r = 0; r < 16; ++r) {
    const int crow = (r & 3) + 8 * (r >> 2) + 4 * hi;
    const float inv = __shfl(linv, crow);    // lane crow holds denom(q=crow)
    const int qg = qt * 128 + wave * 32 + crow;
    const size_t orow = ((size_t)b * 4096 + qg) * 2048 + h * 128;
#pragma unroll
    for (int dt = 0; dt < 4; ++dt)
      ao[orow + dt * 32 + l31] = f2bf(o[dt][r] * inv);
  }
}

// ---------------------------------------------------------------------------
extern "C" void kernel_launch(void* const* d_in, const int* in_sizes, int n_in,
                              void* d_out, int out_size, void* d_ws, size_t ws_size,
                              hipStream_t stream) {
  (void)in_sizes; (void)n_in; (void)out_size; (void)ws_size;
  const float* x      = (const float*)d_in[0];
  const float* y      = (const float*)d_in[1];
  const float* x_cos  = (const float*)d_in[2];
  const float* x_sin  = (const float*)d_in[3];
  const float* y_cos  = (const float*)d_in[4];
  const float* y_sin  = (const float*)d_in[5];
  const float* Wq     = (const float*)d_in[6];
  const float* bq     = (const float*)d_in[7];
  const float* Wk     = (const float*)d_in[8];
  const float* bk     = (const float*)d_in[9];
  const float* Wv     = (const float*)d_in[10];
  const float* bv     = (const float*)d_in[11];
  const float* Wo     = (const float*)d_in[12];
  const float* bo     = (const float*)d_in[13];
  const float* rmsq_w = (const float*)d_in[14];
  const float* rmsk_w = (const float*)d_in[15];
  const float* ln_w   = (const float*)d_in[16];
  const float* ln_b   = (const float*)d_in[17];

  char* ws = (char*)d_ws;
  // ws lifetimes (total 130,023,424 B):
  //  xb    [0, 33.5M)     : prep -> gemm_dual(Q);  qr overlays after.
  //  Wqb   [33.5, 41.9M)  : prep -> gemm_dual;     kr overlays after.
  //  Wkb/Wvb [41.9,50.3M) : prep -> gemm_dual;     vt overlays after.
  //  Wob   [50.3, 58.7M)  : prep -> final gemm_f32 (never clobbered).
  //  ynb   [58.7, 62.9M)  : prep -> gemm_dual(KV).
  //  qpre  [62.9, 96.5M)  : gemm_dual -> post;     ao overlays after.
  //  kvpA  [96.5,113.2M)  : gemm_dual -> post.
  //  kvpB  [113.2,130.0M) : gemm_dual -> post.
  unsigned short* xb    = (unsigned short*)(ws + 0);
  unsigned short* Wqb   = (unsigned short*)(ws + 33554432);
  unsigned short* Wkb   = (unsigned short*)(ws + 41943040);
  unsigned short* Wvb   = (unsigned short*)(ws + 46137344);
  unsigned short* Wob   = (unsigned short*)(ws + 50331648);
  unsigned short* ynb   = (unsigned short*)(ws + 58720256);
  unsigned short* qpre  = (unsigned short*)(ws + 62914560);
  unsigned short* kvpA  = (unsigned short*)(ws + 96468992);
  unsigned short* kvpB  = (unsigned short*)(ws + 113246208);
  unsigned short* qr    = xb;                                  // over xb (dead)
  unsigned short* kr    = Wqb;                                 // over Wqb (dead)
  unsigned short* vt    = Wkb;                                 // over Wkb/Wvb (dead)
  unsigned short* ao    = qpre;                                // over qpre (dead)
  (void)Wvb;

  const float qscale = 1.4426950408889634f * 0.08838834764831843f; // log2e/sqrt(128)

  prep_kernel<<<3584, 256, 0, stream>>>(y, ln_w, ln_b, ynb, x, Wq, Wk, Wv, Wo,
                                        xb, Wqb, Wkb, Wvb, Wob);
  gemm_dual<<<256, 512, 0, stream>>>(xb, Wqb, bq, qpre, ynb, Wkb, kvpA, kvpB);
  post_kernel<<<10752, 256, 0, stream>>>(qpre, rmsq_w, x_cos, x_sin, qr,
                                         kvpA, kvpB, bk, bv, rmsk_w,
                                         y_cos, y_sin, kr, vt, qscale);
  attn_kernel<<<1024, 256, 0, stream>>>(qr, kr, vt, ao);
  gemm_f32<<<256, 512, 0, stream>>>(ao, Wob, bo, (float*)d_out, 8192, 2048, 2048);
}

// Round 16
// 302.721 us; speedup vs baseline: 1.0057x; 1.0057x over previous
//
#include <hip/hip_runtime.h>

// ---------------------------------------------------------------------------
// ConditionalCrossAttentionBlock: LN -> K/V proj -> RMS(Q proj) -> RoPE ->
// 16-head cross attention (LQ=4096, LKV=1024, Dh=128) -> O proj.
// R16: removed per-phase lgkmcnt(0)+sched_barrier(0) order-pin from the
// 8-phase GEMM (m141 lesson: pinning defeats the compiler's fine-grained
// lgkmcnt interleave of ds_read with MFMA). Sync safety unchanged: all
// fragment reads are consumed by MFMAs before each phase's closing barrier.
// Rest identical to R15.
// ---------------------------------------------------------------------------

typedef __attribute__((ext_vector_type(8))) short    short8;
typedef __attribute__((ext_vector_type(8))) unsigned short ushort8;
typedef __attribute__((ext_vector_type(4))) unsigned short ushort4v;
typedef __attribute__((ext_vector_type(4))) float    f32x4;
typedef __attribute__((ext_vector_type(16))) float   f32x16;
typedef __attribute__((ext_vector_type(4))) unsigned int uint4v;

#define DEV __device__ __forceinline__

DEV unsigned short f2bf(float f) {
  unsigned int u = __builtin_bit_cast(unsigned int, f);
  u += 0x7FFFu + ((u >> 16) & 1u);        // RNE, inputs are finite
  return (unsigned short)(u >> 16);
}
DEV float bf2f(unsigned short h) {
  return __builtin_bit_cast(float, ((unsigned int)h) << 16);
}
DEV unsigned int cvtpk_bf16(float lo, float hi) {
  unsigned int r;
  asm("v_cvt_pk_bf16_f32 %0, %1, %2" : "=v"(r) : "v"(lo), "v"(hi));
  return r;
}
DEV short8 mk8(unsigned a, unsigned b, unsigned c, unsigned d) {
  uint4v t; t.x = a; t.y = b; t.z = c; t.w = d;
  return __builtin_bit_cast(short8, t);
}

DEV void gload_lds16(const void* g, void* l) {
  __builtin_amdgcn_global_load_lds(
      (const __attribute__((address_space(1))) void*)g,
      (__attribute__((address_space(3))) void*)l, 16, 0, 0);
}

// ---------------------------------------------------------------------------
// prep: blocks [0,2048) = LayerNorm rows; [2048,3584) = grid-stride f32->bf16
// over {x, Wq, Wk, Wv, Wo}.
// ---------------------------------------------------------------------------
__global__ __launch_bounds__(256) void prep_kernel(const float* __restrict__ y,
                                                   const float* __restrict__ lnw,
                                                   const float* __restrict__ lnb,
                                                   unsigned short* __restrict__ yn,
                                                   const float* __restrict__ x,
                                                   const float* __restrict__ Wq,
                                                   const float* __restrict__ Wk,
                                                   const float* __restrict__ Wv,
                                                   const float* __restrict__ Wo,
                                                   unsigned short* __restrict__ xb,
                                                   unsigned short* __restrict__ Wqb,
                                                   unsigned short* __restrict__ Wkb,
                                                   unsigned short* __restrict__ Wvb,
                                                   unsigned short* __restrict__ Wob) {
  const int t = threadIdx.x;
  if (blockIdx.x < 2048) {
    const int row = blockIdx.x;
    const float* yr = y + (size_t)row * 1024;
    float4 v = *(const float4*)(yr + t * 4);
    float s1 = v.x + v.y + v.z + v.w;
    float s2 = v.x * v.x + v.y * v.y + v.z * v.z + v.w * v.w;
#pragma unroll
    for (int m = 1; m < 64; m <<= 1) {
      s1 += __shfl_xor(s1, m);
      s2 += __shfl_xor(s2, m);
    }
    __shared__ float red[8];
    const int wave = t >> 6, lane = t & 63;
    if (lane == 0) { red[wave] = s1; red[4 + wave] = s2; }
    __syncthreads();
    s1 = red[0] + red[1] + red[2] + red[3];
    s2 = red[4] + red[5] + red[6] + red[7];
    const float mu = s1 * (1.0f / 1024.0f);
    const float var = s2 * (1.0f / 1024.0f) - mu * mu;
    const float rs = rsqrtf(var + 1e-6f);
    ushort4v o;
    o.x = f2bf((v.x - mu) * rs * lnw[t * 4 + 0] + lnb[t * 4 + 0]);
    o.y = f2bf((v.y - mu) * rs * lnw[t * 4 + 1] + lnb[t * 4 + 1]);
    o.z = f2bf((v.z - mu) * rs * lnw[t * 4 + 2] + lnb[t * 4 + 2]);
    o.w = f2bf((v.w - mu) * rs * lnw[t * 4 + 3] + lnb[t * 4 + 3]);
    *(ushort4v*)(yn + (size_t)row * 1024 + t * 4) = o;
    return;
  }
  const int nx = 4194304, nwq = 1048576, nwk = 524288, nwv = 524288;
  const int total = 7340032;
  int i = (blockIdx.x - 2048) * 256 + t;
  const int stride = 1536 * 256;
  for (; i < total; i += stride) {
    int j = i;
    const float* s; unsigned short* d;
    if (j < nx) { s = x; d = xb; }
    else if ((j -= nx) < nwq) { s = Wq; d = Wqb; }
    else if ((j -= nwq) < nwk) { s = Wk; d = Wkb; }
    else if ((j -= nwk) < nwv) { s = Wv; d = Wvb; }
    else { j -= nwv; s = Wo; d = Wob; }
    float4 v = *(const float4*)(s + (size_t)j * 4);
    ushort4v o;
    o.x = f2bf(v.x); o.y = f2bf(v.y); o.z = f2bf(v.z); o.w = f2bf(v.w);
    *(ushort4v*)(d + (size_t)j * 4) = o;
  }
}

// ---------------------------------------------------------------------------
// 256x256 8-phase pipelined GEMM body (T2+T3+T4+T5).
// C = A[M,K]@W[N,K]^T (+bias). ldRow = row stride in elements (>= K).
// EPI==0: bf16 out + bias; EPI==1: f32 out + bias; EPI==2: bf16 out, no bias.
// ---------------------------------------------------------------------------
template <int EPI>
DEV void gemm256_body(const unsigned short* __restrict__ A,
                      const unsigned short* __restrict__ W,
                      const float* __restrict__ bias0,
                      const float* __restrict__ bias1,
                      int nsplit, void* __restrict__ Cout,
                      int M, int N, int K, int ldRow,
                      int bidLocal, int nwg, char* ldsb, int tid) {
  const int wave = tid >> 6, lane = tid & 63;
  const int lg = lane >> 4, l15 = lane & 15;
  const int wm = wave >> 2, wn = wave & 3;

  const int wgid = (bidLocal & 7) * (nwg >> 3) + (bidLocal >> 3);
  const int nbn = N >> 8;
  const int m0 = (wgid / nbn) * 256;
  const int n0 = (wgid % nbn) * 256;

  const char* Ab = (const char*)A;
  const char* Wb = (const char*)W;
  const size_t ld = (size_t)ldRow * 2;
  const int NT = K >> 6;
  const int NI = NT >> 1;

  const int prow = tid >> 3;
  const int psw  = ((tid * 16) & 127) ^ ((prow & 7) << 4);
  const int pdst = tid * 16;
  const char* pAg = Ab + (size_t)(m0 + prow) * ld + psw;
  const char* pBg = Wb + (size_t)(n0 + prow) * ld + psw;

  f32x4 acc[8][4] = {};
  short8 af[4][2];
  short8 bf[4][2];

#define LDSB(BUF, SEG) (ldsb + ((BUF) * 4 + (SEG)) * 16384)

#define STG(BUF, HALF, ISB, TAU) do {                                         \
    const char* _g = ((ISB) ? pBg : pAg) + (size_t)(HALF) * 128 * ld +        \
                     (size_t)(TAU) * 128;                                     \
    char* _l = LDSB(BUF, (ISB) * 2 + (HALF));                                 \
    gload_lds16(_g, _l + pdst);                                               \
    gload_lds16(_g + 64 * ld, _l + pdst + 8192);                              \
  } while (0)

#define LDA(BUF, H) do {                                                      \
    const char* _b = LDSB(BUF, wm);                                           \
    _Pragma("unroll") for (int mfl = 0; mfl < 4; ++mfl) {                     \
      const int _r = (H) * 64 + mfl * 16 + l15;                               \
      _Pragma("unroll") for (int ks = 0; ks < 2; ++ks)                        \
        af[mfl][ks] = *(const short8*)(_b + _r * 128 +                        \
                        ((ks * 64 + lg * 16) ^ ((_r & 7) << 4)));             \
    }                                                                         \
  } while (0)

#define LDB(BUF, G) do {                                                      \
    const char* _b = LDSB(BUF, 2 + (wn >> 1));                                \
    _Pragma("unroll") for (int nfl = 0; nfl < 2; ++nfl) {                     \
      const int _r = (wn & 1) * 64 + (G) * 32 + nfl * 16 + l15;               \
      _Pragma("unroll") for (int ks = 0; ks < 2; ++ks)                        \
        bf[(G) * 2 + nfl][ks] = *(const short8*)(_b + _r * 128 +              \
                        ((ks * 64 + lg * 16) ^ ((_r & 7) << 4)));             \
    }                                                                         \
  } while (0)

#define MFMA_Q(H, G) do {                                                     \
    __builtin_amdgcn_s_setprio(1);                                            \
    _Pragma("unroll") for (int ks = 0; ks < 2; ++ks)                          \
    _Pragma("unroll") for (int mfl = 0; mfl < 4; ++mfl)                       \
    _Pragma("unroll") for (int nfl = 0; nfl < 2; ++nfl)                       \
      acc[(H) * 4 + mfl][(G) * 2 + nfl] =                                     \
        __builtin_amdgcn_mfma_f32_16x16x32_bf16(af[mfl][ks],                  \
            bf[(G) * 2 + nfl][ks], acc[(H) * 4 + mfl][(G) * 2 + nfl], 0,0,0); \
    __builtin_amdgcn_s_setprio(0);                                            \
  } while (0)

#define BAR() __builtin_amdgcn_s_barrier()
#define VM4() asm volatile("s_waitcnt vmcnt(4)" ::: "memory")
#define VM0() asm volatile("s_waitcnt vmcnt(0)" ::: "memory")

  STG(0, 0, 0, 0); STG(0, 1, 0, 0); STG(0, 0, 1, 0); STG(0, 1, 1, 0);
  STG(1, 0, 1, 1); STG(1, 1, 1, 1);
  VM4(); BAR();

  for (int t = 0; t < NI - 1; ++t) {
    const int t2 = 2 * t;
    LDA(0, 0); LDB(0, 0); STG(1, 0, 0, t2 + 1);
    BAR(); MFMA_Q(0, 0); BAR();
    LDB(0, 1); STG(1, 1, 0, t2 + 1);
    BAR(); MFMA_Q(0, 1); BAR();
    LDA(0, 1); STG(0, 0, 1, t2 + 2);
    BAR(); MFMA_Q(1, 1); BAR();
    STG(0, 1, 1, t2 + 2);
    BAR(); MFMA_Q(1, 0); VM4(); BAR();
    LDA(1, 0); LDB(1, 0); STG(0, 0, 0, t2 + 2);
    BAR(); MFMA_Q(0, 0); BAR();
    LDB(1, 1); STG(0, 1, 0, t2 + 2);
    BAR(); MFMA_Q(0, 1); BAR();
    LDA(1, 1); STG(1, 0, 1, t2 + 3);
    BAR(); MFMA_Q(1, 1); BAR();
    STG(1, 1, 1, t2 + 3);
    BAR(); MFMA_Q(1, 0); VM4(); BAR();
  }

  LDA(0, 0); LDB(0, 0); STG(1, 0, 0, NT - 1);
  BAR(); MFMA_Q(0, 0); BAR();
  LDB(0, 1); STG(1, 1, 0, NT - 1);
  BAR(); MFMA_Q(0, 1); BAR();
  LDA(0, 1);
  BAR(); MFMA_Q(1, 1); BAR();
  BAR(); MFMA_Q(1, 0); VM0(); BAR();
  LDA(1, 0); LDB(1, 0); MFMA_Q(0, 0);
  LDB(1, 1); MFMA_Q(0, 1);
  LDA(1, 1); MFMA_Q(1, 1);
  MFMA_Q(1, 0);

#undef STG
#undef LDA
#undef LDB
#undef MFMA_Q
#undef BAR
#undef VM4
#undef VM0
#undef LDSB

#pragma unroll
  for (int nf = 0; nf < 4; ++nf) {
    const int n = n0 + wn * 64 + nf * 16 + l15;
    float bv = 0.f;
    if constexpr (EPI != 2) bv = (n < nsplit) ? bias0[n] : bias1[n - nsplit];
#pragma unroll
    for (int mf = 0; mf < 8; ++mf) {
      const int mB = m0 + wm * 128 + mf * 16 + lg * 4;
#pragma unroll
      for (int r = 0; r < 4; ++r) {
        const float v = acc[mf][nf][r] + bv;
        if constexpr (EPI == 1)
          ((float*)Cout)[(size_t)(mB + r) * N + n] = v;
        else
          ((unsigned short*)Cout)[(size_t)(mB + r) * N + n] = f2bf(v);
      }
    }
  }
}

// Every block: Q tile (32 units) then one KV K-half tile (8 units). Grid 256.
__global__ __launch_bounds__(512, 2) void gemm_dual(const unsigned short* __restrict__ xb,
                                                    const unsigned short* __restrict__ Wqb,
                                                    const float* __restrict__ bq,
                                                    unsigned short* __restrict__ qpre,
                                                    const unsigned short* __restrict__ ynb,
                                                    const unsigned short* __restrict__ Wkb,
                                                    unsigned short* __restrict__ kvpA,
                                                    unsigned short* __restrict__ kvpB) {
  __shared__ __align__(16) char lds[2][4][16384];
  gemm256_body<0>(xb, Wqb, bq, bq, 2048, qpre, 8192, 2048, 2048, 2048,
                  blockIdx.x, 256, &lds[0][0][0], threadIdx.x);
  __syncthreads();   // all waves done with LDS before restaging
  const int kvt = blockIdx.x & 127, khalf = blockIdx.x >> 7;
  gemm256_body<2>(ynb + khalf * 512, Wkb + khalf * 512, nullptr, nullptr, 0,
                  khalf ? kvpB : kvpA, 2048, 4096, 512, 1024,
                  kvt, 128, &lds[0][0][0], threadIdx.x);
}

// O projection (f32 out).
__global__ __launch_bounds__(512, 2) void gemm_f32(const unsigned short* __restrict__ A,
                                                   const unsigned short* __restrict__ W,
                                                   const float* __restrict__ bias,
                                                   float* __restrict__ C,
                                                   int M, int N, int K) {
  __shared__ __align__(16) char lds[2][4][16384];
  gemm256_body<1>(A, W, bias, bias, N, C, M, N, K, K,
                  blockIdx.x, 256, &lds[0][0][0], threadIdx.x);
}

// ---------------------------------------------------------------------------
// post: blocks [0,8192) rmsrope_q; [8192,10240) rmsrope_k (sum partials +
// bias); [10240,10752) vtrans (sum partials + bias).
// ---------------------------------------------------------------------------
DEV void rmsrope2_body(const unsigned short* __restrict__ in,
                       const unsigned short* __restrict__ in2,
                       const float* __restrict__ bias,
                       const float* __restrict__ w,
                       const float* __restrict__ cs,
                       const float* __restrict__ sn,
                       unsigned short* __restrict__ out,
                       int L, int ldin, float scale, int row,
                       float* srow, float* red) {
  const int t = threadIdx.x;
  ushort8 v = *(const ushort8*)(in + (size_t)row * ldin + t * 8);
  float vals[8];
  if (in2) {
    ushort8 v2 = *(const ushort8*)(in2 + (size_t)row * ldin + t * 8);
#pragma unroll
    for (int j = 0; j < 8; ++j) vals[j] = bf2f(v[j]) + bf2f(v2[j]) + bias[t * 8 + j];
  } else {
#pragma unroll
    for (int j = 0; j < 8; ++j) vals[j] = bf2f(v[j]);
  }
  float ss = 0.f;
#pragma unroll
  for (int j = 0; j < 8; ++j) { ss += vals[j] * vals[j]; srow[t * 8 + j] = vals[j]; }
#pragma unroll
  for (int m = 1; m < 64; m <<= 1) ss += __shfl_xor(ss, m);
  const int wave = t >> 6, lane = t & 63;
  if (lane == 0) red[wave] = ss;
  __syncthreads();
  const float tot = red[0] + red[1] + red[2] + red[3];
  const float rms = rsqrtf(tot * (1.0f / 2048.0f) + 1e-6f);

  const int n0 = t * 8;
  const int d0 = n0 & 127;
  const int hh = n0 >> 7;
  const float sign = (d0 < 64) ? -1.0f : 1.0f;
  const float* cb = cs + (size_t)row * 128 + d0;
  const float* sb = sn + (size_t)row * 128 + d0;
  ushort8 ou;
#pragma unroll
  for (int j = 0; j < 8; ++j) {
    const float self = vals[j] * rms * w[n0 + j];
    const float part = srow[(n0 ^ 64) + j] * rms * w[(n0 ^ 64) + j];
    ou[j] = f2bf((self * cb[j] + sign * part * sb[j]) * scale);
  }
  const int b = row / L, l = row - (row / L) * L;
  *(ushort8*)(out + (((size_t)(b * 16 + hh)) * L + l) * 128 + d0) = ou;
}

DEV void vtrans2_body(const unsigned short* __restrict__ va,
                      const unsigned short* __restrict__ vb,
                      const float* __restrict__ bv,
                      unsigned short* __restrict__ vt, int ldv, int bid,
                      unsigned short (*lt)[130]) {
  const int kt = bid & 15, bh = bid >> 4;
  const int h = bh & 15, b = bh >> 4;
  const int t = threadIdx.x;
  const int i0 = t >> 4, c0 = (t & 15) * 8;
  const size_t sbase = ((size_t)(b * 1024 + kt * 64)) * ldv + h * 128;
#pragma unroll
  for (int ii = 0; ii < 4; ++ii) {
    const int i = i0 + ii * 16;
    ushort8 a = *(const ushort8*)(va + sbase + (size_t)i * ldv + c0);
    ushort8 bb = *(const ushort8*)(vb + sbase + (size_t)i * ldv + c0);
#pragma unroll
    for (int j = 0; j < 8; ++j)
      lt[i][c0 + j] = f2bf(bf2f(a[j]) + bf2f(bb[j]) + bv[h * 128 + c0 + j]);
  }
  __syncthreads();
  const int d0 = t >> 3, j0 = (t & 7) * 8;
  unsigned short* dst = vt + (size_t)bh * 128 * 1024 + kt * 64;
#pragma unroll
  for (int dd = 0; dd < 4; ++dd) {
    const int d = d0 + dd * 32;
    ushort8 o;
#pragma unroll
    for (int jj = 0; jj < 8; ++jj) o[jj] = lt[j0 + jj][d];
    *(ushort8*)(dst + (size_t)d * 1024 + j0) = o;
  }
}

__global__ __launch_bounds__(256) void post_kernel(const unsigned short* __restrict__ qpre,
                                                   const float* __restrict__ rmsq_w,
                                                   const float* __restrict__ x_cos,
                                                   const float* __restrict__ x_sin,
                                                   unsigned short* __restrict__ qr,
                                                   const unsigned short* __restrict__ kvpA,
                                                   const unsigned short* __restrict__ kvpB,
                                                   const float* __restrict__ bk,
                                                   const float* __restrict__ bv,
                                                   const float* __restrict__ rmsk_w,
                                                   const float* __restrict__ y_cos,
                                                   const float* __restrict__ y_sin,
                                                   unsigned short* __restrict__ kr,
                                                   unsigned short* __restrict__ vt,
                                                   float qscale) {
  __shared__ __align__(16) float srow[2048];
  __shared__ float red[4];
  __shared__ unsigned short lt[64][130];
  const int b = blockIdx.x;
  if (b < 8192) {
    rmsrope2_body(qpre, nullptr, nullptr, rmsq_w, x_cos, x_sin, qr,
                  4096, 2048, qscale, b, srow, red);
  } else if (b < 10240) {
    rmsrope2_body(kvpA, kvpB, bk, rmsk_w, y_cos, y_sin, kr,
                  1024, 4096, 1.0f, b - 8192, srow, red);
  } else {
    vtrans2_body(kvpA + 2048, kvpB + 2048, bv, vt, 4096, b - 10240, lt);
  }
}

// ---------------------------------------------------------------------------
// Flash cross-attention (R15): 256-thread blocks (4 waves x 32 q), KVBLK=64,
// LDS 64KB -> 2 independent blocks/CU. Per-wave math identical to R8/R10.
// ---------------------------------------------------------------------------
__global__ __launch_bounds__(256, 2) void attn_kernel(const unsigned short* __restrict__ q,
                                                      const unsigned short* __restrict__ k,
                                                      const unsigned short* __restrict__ vt,
                                                      unsigned short* __restrict__ ao) {
  __shared__ __align__(16) char sK[2][64 * 256];    // [buf][kv 64][128 d]
  __shared__ __align__(16) char sV[2][64 * 256];    // [buf] paired-d

  // XCD-grouped swizzle: all 32 q-tiles of one bh land on one XCD.
  const int bid0 = blockIdx.x;                      // 1024 = 32 bh * 32 qtiles
  const int bid = (bid0 & 7) * 128 + (bid0 >> 3);
  const int qt = bid & 31, bh = bid >> 5;
  const int tid = threadIdx.x;
  const int wave = tid >> 6, lane = tid & 63;
  const int l31 = lane & 31, hi = lane >> 5;
  const bool hib = (hi != 0);

  const unsigned short* qbase = q + (((size_t)bh * 4096) + qt * 128 + wave * 32) * 128;
  const char* kbase = (const char*)(k + (size_t)bh * 1024 * 128);
  const char* vbase = (const char*)(vt + (size_t)bh * 128 * 1024);

  short8 qb[8];
#pragma unroll
  for (int step = 0; step < 8; ++step)
    qb[step] = *(const short8*)(qbase + (size_t)l31 * 128 + step * 16 + hi * 8);

  f32x16 o[4] = {};        // o[dt]: O[q=crow(r,hi)][d=dt*32+l31]
  float lsum = 0.f;

#define STAGE_KV(BUF, KV0) do {                                              \
    _Pragma("unroll")                                                        \
    for (int i = 0; i < 4; ++i) {                                            \
      const int p = (i * 256 + tid) * 16;                                    \
      const int row = p >> 8;                                                \
      const int si = (p & 255) ^ ((row & 15) << 4);                          \
      gload_lds16(kbase + (size_t)((KV0) + row) * 256 + si, sK[BUF] + p);    \
    }                                                                        \
    _Pragma("unroll")                                                        \
    for (int i = 0; i < 4; ++i) {                                            \
      const int p = (i * 256 + tid) * 16;                                    \
      const int row = p >> 8;                                                \
      const int si = (p & 255) ^ ((row & 15) << 4);                          \
      const int d = 2 * row + (si >> 7);                                     \
      gload_lds16(vbase + (size_t)d * 2048 + (KV0) * 2 + (si & 127),         \
                  sV[BUF] + p);                                              \
    }                                                                        \
  } while (0)

#define QK(K, S0, S1) do {                                                   \
    const int ksw = (l31 & 15) << 4;                                         \
    _Pragma("unroll") for (int step = 0; step < 8; ++step) {                 \
      const int cb2 = step * 32 + hi * 16;                                   \
      short8 kf0 = *(const short8*)((K) + l31 * 256 + (cb2 ^ ksw));          \
      short8 kf1 = *(const short8*)((K) + (32 + l31) * 256 + (cb2 ^ ksw));   \
      S0 = __builtin_amdgcn_mfma_f32_32x32x16_bf16(kf0, qb[step], S0, 0,0,0);\
      S1 = __builtin_amdgcn_mfma_f32_32x32x16_bf16(kf1, qb[step], S1, 0,0,0);\
    }                                                                        \
  } while (0)

#define SOFTMAX_PV(V, SS, F) do {                                            \
    float p_[16];                                                            \
    _Pragma("unroll") for (int r = 0; r < 16; ++r) p_[r] = exp2f((SS)[r]);   \
    lsum += (((p_[0]+p_[1])+(p_[2]+p_[3])) + ((p_[4]+p_[5])+(p_[6]+p_[7])))  \
          + (((p_[8]+p_[9])+(p_[10]+p_[11])) + ((p_[12]+p_[13])+(p_[14]+p_[15])));\
    const unsigned w0 = cvtpk_bf16(p_[0], p_[1]),  w1 = cvtpk_bf16(p_[2], p_[3]), \
                   w2 = cvtpk_bf16(p_[4], p_[5]),  w3 = cvtpk_bf16(p_[6], p_[7]), \
                   w4 = cvtpk_bf16(p_[8], p_[9]),  w5 = cvtpk_bf16(p_[10], p_[11]),\
                   w6 = cvtpk_bf16(p_[12], p_[13]),w7 = cvtpk_bf16(p_[14], p_[15]);\
    const unsigned x0 = (unsigned)__shfl_xor((int)(hib ? w0 : w2), 32);      \
    const unsigned x1 = (unsigned)__shfl_xor((int)(hib ? w1 : w3), 32);      \
    const unsigned x2 = (unsigned)__shfl_xor((int)(hib ? w4 : w6), 32);      \
    const unsigned x3 = (unsigned)__shfl_xor((int)(hib ? w5 : w7), 32);      \
    const short8 fr0 = mk8(hib ? x0 : w0, hib ? x1 : w1,                     \
                           hib ? w2 : x0, hib ? w3 : x1);                    \
    const short8 fr1 = mk8(hib ? x2 : w4, hib ? x3 : w5,                     \
                           hib ? w6 : x2, hib ? w7 : x3);                    \
    _Pragma("unroll") for (int kstep = 0; kstep < 2; ++kstep) {              \
      const short8 pa = kstep ? fr1 : fr0;                                   \
      const int colb = (F) * 64 + kstep * 32 + hi * 16;                      \
      _Pragma("unroll") for (int dt = 0; dt < 4; ++dt) {                     \
        const int vrow = dt * 16 + (l31 >> 1);                               \
        const int inner = (l31 & 1) * 128 + colb;                            \
        short8 vf = *(const short8*)((V) + vrow * 256 +                      \
                                     (inner ^ ((vrow & 15) << 4)));          \
        o[dt] = __builtin_amdgcn_mfma_f32_32x32x16_bf16(pa, vf, o[dt], 0,0,0);\
      }                                                                      \
    }                                                                        \
  } while (0)

#define TILE(BUF) do {                                                       \
    f32x16 s0 = {}, s1 = {};                                                 \
    QK(sK[BUF], s0, s1);                                                     \
    SOFTMAX_PV(sV[BUF], s0, 0);                                              \
    SOFTMAX_PV(sV[BUF], s1, 1);                                              \
  } while (0)

  STAGE_KV(0, 0);
  __syncthreads();

#pragma unroll 1
  for (int kt2 = 0; kt2 < 8; ++kt2) {
    STAGE_KV(1, (2 * kt2 + 1) * 64);     // prefetch odd tile into buf1
    TILE(0);
    __syncthreads();
    if (kt2 < 7) STAGE_KV(0, (2 * kt2 + 2) * 64);  // prefetch even tile
    TILE(1);
    __syncthreads();
  }
#undef STAGE_KV
#undef QK
#undef SOFTMAX_PV
#undef TILE

  lsum += __shfl_xor(lsum, 32);
  const float linv = 1.0f / lsum;
  const int b = bh >> 4, h = bh & 15;
#pragma unroll
  for (int r = 0; r < 16; ++r) {
    const int crow = (r & 3) + 8 * (r >> 2) + 4 * hi;
    const float inv = __shfl(linv, crow);    // lane crow holds denom(q=crow)
    const int qg = qt * 128 + wave * 32 + crow;
    const size_t orow = ((size_t)b * 4096 + qg) * 2048 + h * 128;
#pragma unroll
    for (int dt = 0; dt < 4; ++dt)
      ao[orow + dt * 32 + l31] = f2bf(o[dt][r] * inv);
  }
}

// ---------------------------------------------------------------------------
extern "C" void kernel_launch(void* const* d_in, const int* in_sizes, int n_in,
                              void* d_out, int out_size, void* d_ws, size_t ws_size,
                              hipStream_t stream) {
  (void)in_sizes; (void)n_in; (void)out_size; (void)ws_size;
  const float* x      = (const float*)d_in[0];
  const float* y      = (const float*)d_in[1];
  const float* x_cos  = (const float*)d_in[2];
  const float* x_sin  = (const float*)d_in[3];
  const float* y_cos  = (const float*)d_in[4];
  const float* y_sin  = (const float*)d_in[5];
  const float* Wq     = (const float*)d_in[6];
  const float* bq     = (const float*)d_in[7];
  const float* Wk     = (const float*)d_in[8];
  const float* bk     = (const float*)d_in[9];
  const float* Wv     = (const float*)d_in[10];
  const float* bv     = (const float*)d_in[11];
  const float* Wo     = (const float*)d_in[12];
  const float* bo     = (const float*)d_in[13];
  const float* rmsq_w = (const float*)d_in[14];
  const float* rmsk_w = (const float*)d_in[15];
  const float* ln_w   = (const float*)d_in[16];
  const float* ln_b   = (const float*)d_in[17];

  char* ws = (char*)d_ws;
  // ws lifetimes (total 130,023,424 B):
  //  xb    [0, 33.5M)     : prep -> gemm_dual(Q);  qr overlays after.
  //  Wqb   [33.5, 41.9M)  : prep -> gemm_dual;     kr overlays after.
  //  Wkb/Wvb [41.9,50.3M) : prep -> gemm_dual;     vt overlays after.
  //  Wob   [50.3, 58.7M)  : prep -> final gemm_f32 (never clobbered).
  //  ynb   [58.7, 62.9M)  : prep -> gemm_dual(KV).
  //  qpre  [62.9, 96.5M)  : gemm_dual -> post;     ao overlays after.
  //  kvpA  [96.5,113.2M)  : gemm_dual -> post.
  //  kvpB  [113.2,130.0M) : gemm_dual -> post.
  unsigned short* xb    = (unsigned short*)(ws + 0);
  unsigned short* Wqb   = (unsigned short*)(ws + 33554432);
  unsigned short* Wkb   = (unsigned short*)(ws + 41943040);
  unsigned short* Wvb   = (unsigned short*)(ws + 46137344);
  unsigned short* Wob   = (unsigned short*)(ws + 50331648);
  unsigned short* ynb   = (unsigned short*)(ws + 58720256);
  unsigned short* qpre  = (unsigned short*)(ws + 62914560);
  unsigned short* kvpA  = (unsigned short*)(ws + 96468992);
  unsigned short* kvpB  = (unsigned short*)(ws + 113246208);
  unsigned short* qr    = xb;                                  // over xb (dead)
  unsigned short* kr    = Wqb;                                 // over Wqb (dead)
  unsigned short* vt    = Wkb;                                 // over Wkb/Wvb (dead)
  unsigned short* ao    = qpre;                                // over qpre (dead)
  (void)Wvb;

  const float qscale = 1.4426950408889634f * 0.08838834764831843f; // log2e/sqrt(128)

  prep_kernel<<<3584, 256, 0, stream>>>(y, ln_w, ln_b, ynb, x, Wq, Wk, Wv, Wo,
                                        xb, Wqb, Wkb, Wvb, Wob);
  gemm_dual<<<256, 512, 0, stream>>>(xb, Wqb, bq, qpre, ynb, Wkb, kvpA, kvpB);
  post_kernel<<<10752, 256, 0, stream>>>(qpre, rmsq_w, x_cos, x_sin, qr,
                                         kvpA, kvpB, bk, bv, rmsk_w,
                                         y_cos, y_sin, kr, vt, qscale);
  attn_kernel<<<1024, 256, 0, stream>>>(qr, kr, vt, ao);
  gemm_f32<<<256, 512, 0, stream>>>(ao, Wob, bo, (float*)d_out, 8192, 2048, 2048);
}